// Round 5
// baseline (362.388 us; speedup 1.0000x reference)
//
#include <hip/hip_runtime.h>
#include <hip/hip_bf16.h>

// MHA forward. Established: inputs fp32, OUTPUT fp32 (R3/R4 bit-identical
// absmax proved compute correct; failure was writing bf16 into an fp32-read
// buffer). Pipeline (all compute bf16 MFMA, fp32 accumulate):
//   transpose weights (fp32->bf16) -> QKV GEMM (fp32 x staged to bf16 LDS,
//   Q pre-scaled 1/8) -> flash attention -> proj GEMM -> fp32 out.
// B=8, N=1024, DIM=768, NH=12, HD=64, M=8192.  WS high-water 55,050,240 B.

typedef __bf16 bf16x8 __attribute__((ext_vector_type(8)));
typedef float f32x4 __attribute__((ext_vector_type(4)));

#define MFMA16(a, b, c) __builtin_amdgcn_mfma_f32_16x16x32_bf16(a, b, c, 0, 0, 0)

__device__ inline __bf16 to_bf16(float f) {
  __hip_bfloat16 h = __float2bfloat16(f);
  return *reinterpret_cast<__bf16*>(&h);
}

// ---------------------------------------------------------------- diagnostic
__global__ void ws_diag_kernel(float* out, int n, float val) {
  int i = blockIdx.x * 256 + threadIdx.x;
  if (i < n) out[i] = val;
}

// ---------------------------------------------------------------- cvt+transpose
// W fp32 [rows][cols] -> Wt bf16 [cols][rows].
__global__ void convert_transpose_kernel(const float* __restrict__ W,
                                         __hip_bfloat16* __restrict__ Wt,
                                         int rows, int cols) {
  __shared__ __hip_bfloat16 tile[32][33];
  const int tc = blockIdx.x * 32, tr = blockIdx.y * 32;
  const int tx = threadIdx.x, ty = threadIdx.y;  // block (32,8)
#pragma unroll
  for (int i = 0; i < 4; ++i) {
    int r = ty + i * 8;
    tile[r][tx] = __float2bfloat16(W[(size_t)(tr + r) * cols + tc + tx]);
  }
  __syncthreads();
#pragma unroll
  for (int i = 0; i < 4; ++i) {
    int r = ty + i * 8;
    Wt[(size_t)(tc + r) * rows + tr + tx] = tile[tx][r];
  }
}

// ---------------------------------------------------------------- GEMM common
constexpr int GK = 768;
constexpr int LDT = 40;

// ---------------------------------------------------------------- QKV GEMM
// A = x fp32 [8192][768] (staged to bf16 in registers), Bt = WqkvT bf16.
__global__ __launch_bounds__(256) void gemm_qkv_kernel(
    const float* __restrict__ A,        // x fp32
    const __hip_bfloat16* __restrict__ Bt,  // WqkvT [2304][768] bf16
    const float* __restrict__ bias,     // b_qkv fp32 [2304]
    __hip_bfloat16* __restrict__ Qw,    // [96][1024][64] (Q pre-scaled 1/8)
    __hip_bfloat16* __restrict__ Kw,
    __hip_bfloat16* __restrict__ Vw) {
  __shared__ __bf16 As[128 * LDT];
  __shared__ __bf16 Bs[128 * LDT];
  const int tid = threadIdx.x;
  const int lane = tid & 63, wave = tid >> 6;
  const int wr = wave >> 1, wc = wave & 1;
  const int m0 = blockIdx.x * 128, n0 = blockIdx.y * 128;
  const int fr = lane & 15, q4 = lane >> 4;

  f32x4 acc[4][4] = {};

  for (int kt = 0; kt < GK / 32; ++kt) {
    __bf16 areg[2][8];
    int4 breg[2];
#pragma unroll
    for (int i = 0; i < 2; ++i) {
      int s = tid + 256 * i;
      int row = s >> 2, c = (s & 3) * 8;
      float4 a0 = *(const float4*)(A + (size_t)(m0 + row) * GK + kt * 32 + c);
      float4 a1 = *(const float4*)(A + (size_t)(m0 + row) * GK + kt * 32 + c + 4);
      areg[i][0] = to_bf16(a0.x); areg[i][1] = to_bf16(a0.y);
      areg[i][2] = to_bf16(a0.z); areg[i][3] = to_bf16(a0.w);
      areg[i][4] = to_bf16(a1.x); areg[i][5] = to_bf16(a1.y);
      areg[i][6] = to_bf16(a1.z); areg[i][7] = to_bf16(a1.w);
      breg[i] = *(const int4*)(Bt + (size_t)(n0 + row) * GK + kt * 32 + c);
    }
    __syncthreads();
#pragma unroll
    for (int i = 0; i < 2; ++i) {
      int s = tid + 256 * i;
      int row = s >> 2, c = (s & 3) * 8;
      *(int4*)(&As[row * LDT + c]) = *(const int4*)areg[i];
      *(int4*)(&Bs[row * LDT + c]) = breg[i];
    }
    __syncthreads();
    bf16x8 af[4], bfr[4];
#pragma unroll
    for (int i = 0; i < 4; ++i)
      af[i] = *(const bf16x8*)(&As[(wr * 64 + i * 16 + fr) * LDT + q4 * 8]);
#pragma unroll
    for (int j = 0; j < 4; ++j)
      bfr[j] = *(const bf16x8*)(&Bs[(wc * 64 + j * 16 + fr) * LDT + q4 * 8]);
#pragma unroll
    for (int i = 0; i < 4; ++i)
#pragma unroll
      for (int j = 0; j < 4; ++j)
        acc[i][j] = MFMA16(af[i], bfr[j], acc[i][j]);
  }

  // C col = which*768 + h*64 + d; 768 = 6*128 so `which` is tile-uniform.
#pragma unroll
  for (int j = 0; j < 4; ++j) {
    int col = n0 + wc * 64 + j * 16 + fr;
    int which = col / 768;
    int rem = col - which * 768;
    int h = rem >> 6, d = rem & 63;
    float bv = bias[col];
    __hip_bfloat16* dst = (which == 0) ? Qw : (which == 1) ? Kw : Vw;
    float scale = (which == 0) ? 0.125f : 1.0f;  // fold 1/sqrt(64) into Q
#pragma unroll
    for (int i = 0; i < 4; ++i) {
#pragma unroll
      for (int r = 0; r < 4; ++r) {
        int row = m0 + wr * 64 + i * 16 + q4 * 4 + r;  // C-layout row
        int bb = row >> 10, nn = row & 1023;
        float v = (acc[i][j][r] + bv) * scale;
        dst[(((size_t)(bb * 12 + h) * 1024 + nn) << 6) + d] = __float2bfloat16(v);
      }
    }
  }
}

// ---------------------------------------------------------------- proj GEMM
__global__ __launch_bounds__(256) void gemm_proj_kernel(
    const __hip_bfloat16* __restrict__ A,   // attnO bf16 [8192][768]
    const __hip_bfloat16* __restrict__ Bt,  // WprojT bf16 [768][768]
    const float* __restrict__ bias,         // b_proj fp32 [768]
    float* __restrict__ out) {              // d_out fp32 [8192][768]
  __shared__ __bf16 As[128 * LDT];
  __shared__ __bf16 Bs[128 * LDT];
  const int tid = threadIdx.x;
  const int lane = tid & 63, wave = tid >> 6;
  const int wr = wave >> 1, wc = wave & 1;
  const int m0 = blockIdx.x * 128, n0 = blockIdx.y * 128;
  const int fr = lane & 15, q4 = lane >> 4;

  f32x4 acc[4][4] = {};

  for (int kt = 0; kt < GK / 32; ++kt) {
    int4 areg[2], breg[2];
#pragma unroll
    for (int i = 0; i < 2; ++i) {
      int s = tid + 256 * i;
      int row = s >> 2, c = (s & 3) * 8;
      areg[i] = *(const int4*)(A + (size_t)(m0 + row) * GK + kt * 32 + c);
      breg[i] = *(const int4*)(Bt + (size_t)(n0 + row) * GK + kt * 32 + c);
    }
    __syncthreads();
#pragma unroll
    for (int i = 0; i < 2; ++i) {
      int s = tid + 256 * i;
      int row = s >> 2, c = (s & 3) * 8;
      *(int4*)(&As[row * LDT + c]) = areg[i];
      *(int4*)(&Bs[row * LDT + c]) = breg[i];
    }
    __syncthreads();
    bf16x8 af[4], bfr[4];
#pragma unroll
    for (int i = 0; i < 4; ++i)
      af[i] = *(const bf16x8*)(&As[(wr * 64 + i * 16 + fr) * LDT + q4 * 8]);
#pragma unroll
    for (int j = 0; j < 4; ++j)
      bfr[j] = *(const bf16x8*)(&Bs[(wc * 64 + j * 16 + fr) * LDT + q4 * 8]);
#pragma unroll
    for (int i = 0; i < 4; ++i)
#pragma unroll
      for (int j = 0; j < 4; ++j)
        acc[i][j] = MFMA16(af[i], bfr[j], acc[i][j]);
  }

#pragma unroll
  for (int j = 0; j < 4; ++j) {
    int col = n0 + wc * 64 + j * 16 + fr;
    float bv = bias[col];
#pragma unroll
    for (int i = 0; i < 4; ++i) {
#pragma unroll
      for (int r = 0; r < 4; ++r) {
        int row = m0 + wr * 64 + i * 16 + q4 * 4 + r;
        out[(size_t)row * 768 + col] = acc[i][j][r] + bv;
      }
    }
  }
}

// ---------------------------------------------------------------- attention
// One block = (b,h, 128 q-rows). 4 waves x 32 q-rows. KV tiles of 64 keys.
__global__ __launch_bounds__(256) void attn_kernel(
    const __hip_bfloat16* __restrict__ Qw,
    const __hip_bfloat16* __restrict__ Kw,
    const __hip_bfloat16* __restrict__ Vw,
    __hip_bfloat16* __restrict__ O) {  // attnO [8192][768], col = h*64+d
  constexpr int LP = 72;
  __shared__ __bf16 Qs[128 * LP];
  __shared__ __bf16 Ks[64 * LP];
  __shared__ __bf16 Vts[64 * LP];     // V^T: [d][key]
  __shared__ __bf16 Ps[4][32 * LP];   // per-wave P buffer
  const int tid = threadIdx.x;
  const int lane = tid & 63, wave = tid >> 6;
  const int fr = lane & 15, q4 = lane >> 4;
  const int bh = blockIdx.x >> 3, qt = blockIdx.x & 7;
  const __hip_bfloat16* Qb = Qw + ((size_t)bh * 1024 + qt * 128) * 64;
  const __hip_bfloat16* Kb = Kw + (size_t)bh * 1024 * 64;
  const __hip_bfloat16* Vb = Vw + (size_t)bh * 1024 * 64;

  for (int s = tid; s < 1024; s += 256) {
    int row = s >> 3, c = (s & 7) * 8;
    *(int4*)(&Qs[row * LP + c]) = *(const int4*)(Qb + row * 64 + c);
  }

  float m_i[2][4], l_i[2][4];
  f32x4 accO[2][4] = {};
#pragma unroll
  for (int mt = 0; mt < 2; ++mt)
#pragma unroll
    for (int r = 0; r < 4; ++r) { m_i[mt][r] = 0.0f; l_i[mt][r] = 0.f; }

  for (int kt = 0; kt < 16; ++kt) {
    int4 kreg[2], vreg[2];
#pragma unroll
    for (int i = 0; i < 2; ++i) {
      int s = tid + 256 * i;
      int row = s >> 3, c = (s & 7) * 8;
      kreg[i] = *(const int4*)(Kb + (size_t)(kt * 64 + row) * 64 + c);
      vreg[i] = *(const int4*)(Vb + (size_t)(kt * 64 + row) * 64 + c);
    }
    __syncthreads();  // waves done reading Ks/Vts of previous tile
#pragma unroll
    for (int i = 0; i < 2; ++i) {
      int s = tid + 256 * i;
      int row = s >> 3, c = (s & 7) * 8;
      *(int4*)(&Ks[row * LP + c]) = kreg[i];
      __bf16 vt[8];
      *(int4*)vt = vreg[i];
#pragma unroll
      for (int jj = 0; jj < 8; ++jj) Vts[(c + jj) * LP + row] = vt[jj];
    }
    __syncthreads();

    bf16x8 qf[2][2];
#pragma unroll
    for (int mt = 0; mt < 2; ++mt)
#pragma unroll
      for (int ks = 0; ks < 2; ++ks)
        qf[mt][ks] = *(const bf16x8*)(&Qs[(wave * 32 + mt * 16 + fr) * LP + ks * 32 + q4 * 8]);
    f32x4 sc[2][4];
#pragma unroll
    for (int nt = 0; nt < 4; ++nt) {
      bf16x8 kf0 = *(const bf16x8*)(&Ks[(nt * 16 + fr) * LP + q4 * 8]);
      bf16x8 kf1 = *(const bf16x8*)(&Ks[(nt * 16 + fr) * LP + 32 + q4 * 8]);
#pragma unroll
      for (int mt = 0; mt < 2; ++mt) {
        f32x4 z = {};
        z = MFMA16(qf[mt][0], kf0, z);
        sc[mt][nt] = MFMA16(qf[mt][1], kf1, z);
      }
    }

#pragma unroll
    for (int mt = 0; mt < 2; ++mt) {
#pragma unroll
      for (int r = 0; r < 4; ++r) {
        float mx = fmaxf(fmaxf(sc[mt][0][r], sc[mt][1][r]),
                         fmaxf(sc[mt][2][r], sc[mt][3][r]));
#pragma unroll
        for (int off = 1; off < 16; off <<= 1) mx = fmaxf(mx, __shfl_xor(mx, off, 64));
        float mnew = fmaxf(m_i[mt][r], mx);
        float alpha = __expf(m_i[mt][r] - mnew);
        float rs = 0.f;
#pragma unroll
        for (int nt = 0; nt < 4; ++nt) {
          float p = __expf(sc[mt][nt][r] - mnew);
          sc[mt][nt][r] = p;
          rs += p;
        }
#pragma unroll
        for (int off = 1; off < 16; off <<= 1) rs += __shfl_xor(rs, off, 64);
        l_i[mt][r] = l_i[mt][r] * alpha + rs;
        m_i[mt][r] = mnew;
#pragma unroll
        for (int dt = 0; dt < 4; ++dt) accO[mt][dt][r] *= alpha;
      }
    }

#pragma unroll
    for (int mt = 0; mt < 2; ++mt)
#pragma unroll
      for (int nt = 0; nt < 4; ++nt)
#pragma unroll
        for (int r = 0; r < 4; ++r)
          Ps[wave][(mt * 16 + q4 * 4 + r) * LP + nt * 16 + fr] = to_bf16(sc[mt][nt][r]);
    __syncthreads();

#pragma unroll
    for (int ks = 0; ks < 2; ++ks) {
      bf16x8 pf[2];
#pragma unroll
      for (int mt = 0; mt < 2; ++mt)
        pf[mt] = *(const bf16x8*)(&Ps[wave][(mt * 16 + fr) * LP + ks * 32 + q4 * 8]);
#pragma unroll
      for (int dt = 0; dt < 4; ++dt) {
        bf16x8 vf = *(const bf16x8*)(&Vts[(dt * 16 + fr) * LP + ks * 32 + q4 * 8]);
#pragma unroll
        for (int mt = 0; mt < 2; ++mt) accO[mt][dt] = MFMA16(pf[mt], vf, accO[mt][dt]);
      }
    }
  }

  const int h = bh % 12, bb = bh / 12;
#pragma unroll
  for (int mt = 0; mt < 2; ++mt)
#pragma unroll
    for (int dt = 0; dt < 4; ++dt)
#pragma unroll
      for (int r = 0; r < 4; ++r) {
        int row = bb * 1024 + qt * 128 + wave * 32 + mt * 16 + q4 * 4 + r;
        int col = h * 64 + dt * 16 + fr;
        O[(size_t)row * 768 + col] = __float2bfloat16(accO[mt][dt][r] / l_i[mt][r]);
      }
}

// ---------------------------------------------------------------- launch
extern "C" void kernel_launch(void* const* d_in, const int* in_sizes, int n_in,
                              void* d_out, int out_size, void* d_ws, size_t ws_size,
                              hipStream_t stream) {
  const float* x     = (const float*)d_in[0];  // [8192][768]
  const float* Wqkv  = (const float*)d_in[1];  // [768][2304]
  const float* bqkv  = (const float*)d_in[2];  // [2304]
  const float* Wproj = (const float*)d_in[3];  // [768][768]
  const float* bproj = (const float*)d_in[4];  // [768]
  float* out = (float*)d_out;                  // [8192][768] fp32

  constexpr size_t NEEDED = 55050240;
  if (ws_size < NEEDED) {
    ws_diag_kernel<<<(out_size + 255) / 256, 256, 0, stream>>>(
        out, out_size, (float)(ws_size >> 20));
    return;
  }

  char* ws = (char*)d_ws;
  __hip_bfloat16* WqkvT  = (__hip_bfloat16*)(ws);               // 3,538,944 B
  __hip_bfloat16* WprojT = (__hip_bfloat16*)(ws + 3538944);     // 1,179,648 B
  __hip_bfloat16* Qw     = (__hip_bfloat16*)(ws + 4718592);     // 12,582,912 B each
  __hip_bfloat16* Kw     = Qw + (size_t)96 * 1024 * 64;
  __hip_bfloat16* Vw     = Kw + (size_t)96 * 1024 * 64;
  __hip_bfloat16* attnO  = Vw + (size_t)96 * 1024 * 64;         // 12,582,912 B
  // end = 55,050,240

  convert_transpose_kernel<<<dim3(72, 24), dim3(32, 8), 0, stream>>>(
      Wqkv, WqkvT, 768, 2304);
  convert_transpose_kernel<<<dim3(24, 24), dim3(32, 8), 0, stream>>>(
      Wproj, WprojT, 768, 768);
  gemm_qkv_kernel<<<dim3(64, 18), 256, 0, stream>>>(x, WqkvT, bqkv, Qw, Kw, Vw);
  attn_kernel<<<dim3(96 * 8), 256, 0, stream>>>(Qw, Kw, Vw, attnO);
  gemm_proj_kernel<<<dim3(64, 6), 256, 0, stream>>>(attnO, WprojT, bproj, out);
}